// Round 2
// baseline (97.310 us; speedup 1.0000x reference)
//
#include <hip/hip_runtime.h>
#include <math.h>

#define RAD 5
#define SIDE 80
#define SLAB 6400      // 80*80
#define VOL 512000     // 80^3
#define NCH 8          // N*K
#define NCLS 4
#define Q 20           // float4/ushort4 columns per 80-elem row
#define TW 40          // K1 tile extent along w (R10: halo 1.25x, 1280 blocks = 5/CU)
#define NT 2           // w-tiles per axis (80/40)
#define C1 (SIDE*NT)           // 160 K1 slots per channel
#define NBLK1 (NCH*C1)         // 1280 K1 blocks
#define TBS 22                 // tB row stride in float4
#define NBLK2 1000             // K2 blocks (4 h-outputs/thread, 125 per channel)
#define CPB 125                // K2 blocks per channel

// exp(-t^2/32) for t=-5..5 (unnormalized Gaussian, symmetric)
__constant__ float GW[11] = {
    0.45783336177161427f, 0.6065306597126334f, 0.7548396019890073f,
    0.8824969025845955f,  0.969233234476344f,  1.0f,
    0.969233234476344f,   0.8824969025845955f, 0.7548396019890073f,
    0.6065306597126334f,  0.45783336177161427f};

// Module-scope scratch. Slot-based cross-kernel dataflow ONLY:
// R8: device atomics+fences = +100 µs/kernel; R7: grid.sync = +550 µs.
// Kernel boundaries are the only sync primitive used.
__device__ unsigned short g_bufT[(size_t)NCH * VOL];  // bf16 conv'd labels, [c][w][h][d]
__device__ float2 g_part1[NBLK1];             // {S_ip, S_p} per K1 block
__device__ float2 g_part2[NBLK2];             // {num, den} per K2 block

__device__ __forceinline__ unsigned short f2bf(float f) {
    unsigned u = __float_as_uint(f);
    u += 0x7FFFu + ((u >> 16) & 1u);          // round-to-nearest-even
    return (unsigned short)(u >> 16);
}
__device__ __forceinline__ float bf2f(unsigned short h) {
    return __uint_as_float((unsigned)h << 16);
}

// K1: per (c, h, w-tile40): d-conv via register window from global,
// fused channel sums, w-conv via LDS gather, transposed bf16 store to g_bufT.
// R11: exact-trip unrolled loops (phase A: 4x, phase B: 4x) so the compiler
// can software-pipeline the global loads across iterations instead of
// load->wait->compute x4 serially (kernels measured ~3-4x over traffic roofline
// => latency-chain bound, not BW/issue bound).
__global__ void __launch_bounds__(256) convdw_sums_kernel(
        const float* __restrict__ labels, const float* __restrict__ img) {
    const int tile = blockIdx.x;
    const int c   = tile / C1;
    const int rem = tile % C1;
    const int h   = rem / NT;
    const int w0  = (rem % NT) * TW;
    const int n   = c >> 2;

    __shared__ float4 tB[(TW + 10) * TBS];   // d-conv result rows w0-5..w0+TW+4
    __shared__ float sm[8];

    const float4* labc4 = (const float4*)(labels + ((size_t)c * SIDE + h) * SLAB);
    const float4* imgc4 = (const float4*)(img + ((size_t)n * SIDE + h) * SLAB);

    float sip = 0.f, sp = 0.f;
    #pragma unroll
    for (int it = 0; it < 4; ++it) {
        const int i = threadIdx.x + it * 256;
        if (i < (TW + 10) * Q) {              // it<3 provably in-range
            const int r = i / Q, q = i - (i / Q) * Q;
            const int w = w0 - RAD + r;
            float a[20];
            #pragma unroll
            for (int j = 0; j < 20; ++j) a[j] = 0.f;
            if ((unsigned)w < SIDE) {
                const float4* row = labc4 + (size_t)w * Q;
                #pragma unroll
                for (int j = 0; j < 5; ++j) {
                    int qq = q - 2 + j;
                    if (qq >= 0 && qq < Q) {
                        float4 v = row[qq];
                        a[4 * j] = v.x; a[4 * j + 1] = v.y;
                        a[4 * j + 2] = v.z; a[4 * j + 3] = v.w;
                    }
                }
                if (r >= RAD && r < RAD + TW) {   // central rows: fused channel sums
                    float4 v = imgc4[(size_t)w * Q + q];
                    sip += a[8] * v.x + a[9] * v.y + a[10] * v.z + a[11] * v.w;
                    sp  += a[8] + a[9] + a[10] + a[11];
                }
            }
            float s0 = 0.f, s1 = 0.f, s2 = 0.f, s3 = 0.f;
            #pragma unroll
            for (int t = 0; t < 11; ++t) {
                float g = GW[t];
                s0 += g * a[t + 3]; s1 += g * a[t + 4];
                s2 += g * a[t + 5]; s3 += g * a[t + 6];
            }
            tB[r * TBS + q] = make_float4(s0, s1, s2, s3);
        }
    }
    // block-reduce sums (same barrier covers tB completion + sm visibility)
    #pragma unroll
    for (int off = 32; off > 0; off >>= 1) {
        sip += __shfl_down(sip, off);
        sp  += __shfl_down(sp, off);
    }
    const int lane = threadIdx.x & 63;
    const int wid  = threadIdx.x >> 6;
    if (lane == 0) { sm[wid * 2] = sip; sm[wid * 2 + 1] = sp; }
    __syncthreads();
    if (threadIdx.x == 0)
        g_part1[tile] = make_float2(sm[0] + sm[2] + sm[4] + sm[6],
                                    sm[1] + sm[3] + sm[5] + sm[7]);
    // w-conv (11-tap LDS gather) + transposed bf16 ushort4 store
    ushort4* out4 = (ushort4*)g_bufT + ((size_t)c * VOL + (size_t)h * SIDE) / 4;
    #pragma unroll
    for (int it = 0; it < 4; ++it) {
        const int i = threadIdx.x + it * 256;
        if (i < TW * Q) {                     // it<3 provably in-range
            const int rl = i / Q, q = i - (i / Q) * Q;
            float sx = 0.f, sy = 0.f, sz = 0.f, sw = 0.f;
            #pragma unroll
            for (int t = 0; t < 11; ++t) {
                float g = GW[t];
                float4 v = tB[(rl + t) * TBS + q];
                sx += g * v.x; sy += g * v.y; sz += g * v.z; sw += g * v.w;
            }
            ushort4 o;
            o.x = f2bf(sx); o.y = f2bf(sy); o.z = f2bf(sz); o.w = f2bf(sw);
            out4[(size_t)(w0 + rl) * (SLAB / 4) + q] = o;
        }
    }
}

// K2: register sliding-window conv along H from bf16 g_bufT (no LDS conv),
// fused weight + dot. Thread = (c, hq, w, q) producing 4 h-outputs.
// R11: issue ALL mean-independent global loads (win + labels + img) and the
// h-conv BEFORE the mean prologue, and collapse the prologue to a single
// barrier (redundant per-thread mean divide). Previous order hid nothing:
// barrier forbade hoisting 22 loads above the 160-load reduce chain.
__global__ void __launch_bounds__(256) convh_dot_kernel(
        const float* __restrict__ labels, const float* __restrict__ img) {
    const int c   = blockIdx.x / CPB;
    const int rem = (blockIdx.x % CPB) * 256 + threadIdx.x;   // 0..31999
    const int hq  = rem / 1600;          // 20 h-quads
    const int r2  = rem % 1600;
    const int w   = r2 / Q;
    const int q   = r2 % Q;
    const int h0  = hq * 4;
    const int n   = c >> 2;

    __shared__ float sm[8];
    const int lane = threadIdx.x & 63;
    const int wid  = threadIdx.x >> 6;

    // ---- issue mean-independent loads first (all stay in flight) ----
    // sliding window: g_bufT[c][w][h0-5 .. h0+8][q]  (14 ushort4, OOB -> 0)
    const ushort4* bc4 = (const ushort4*)g_bufT + ((size_t)c * VOL + (size_t)w * SLAB) / 4;
    float4 win[14];
    #pragma unroll
    for (int m = 0; m < 14; ++m) {
        int hh = h0 - RAD + m;
        if ((unsigned)hh < SIDE) {
            ushort4 u = bc4[hh * Q + q];
            win[m] = make_float4(bf2f(u.x), bf2f(u.y), bf2f(u.z), bf2f(u.w));
        } else {
            win[m] = make_float4(0.f, 0.f, 0.f, 0.f);
        }
    }
    const float4* labp4 = (const float4*)labels + (size_t)c * (VOL / 4);
    const float4* imgp4 = (const float4*)img + (size_t)n * (VOL / 4);
    float4 lv[4], iv[4];
    #pragma unroll
    for (int k = 0; k < 4; ++k) {
        size_t gi = (size_t)(h0 + k) * (SLAB / 4) + (size_t)w * Q + q;
        lv[k] = labp4[gi];
        iv[k] = imgp4[gi];
    }

    // ---- h-conv (mean-independent) ----
    float csx[4], csy[4], csz[4], csw[4];
    #pragma unroll
    for (int k = 0; k < 4; ++k) {
        float sx = 0.f, sy = 0.f, sz = 0.f, sw = 0.f;
        #pragma unroll
        for (int t = 0; t < 11; ++t) {
            float g = GW[t];
            float4 v = win[k + t];
            sx += g * v.x; sy += g * v.y; sz += g * v.z; sw += g * v.w;
        }
        csx[k] = sx; csy[k] = sy; csz[k] = sz; csw[k] = sw;
    }

    // ---- per-channel mean from K1 partials (single barrier) ----
    float a = 0.f, b = 0.f;
    for (int t = threadIdx.x; t < C1; t += 256) {
        float2 p = g_part1[c * C1 + t];
        a += p.x; b += p.y;
    }
    #pragma unroll
    for (int off = 32; off > 0; off >>= 1) {
        a += __shfl_down(a, off);
        b += __shfl_down(b, off);
    }
    if (lane == 0) { sm[wid * 2] = a; sm[wid * 2 + 1] = b; }
    __syncthreads();
    const float mean = (sm[0] + sm[2] + sm[4] + sm[6]) /
                       (sm[1] + sm[3] + sm[5] + sm[7] + 5.12f);   // VOL*EPS_MEAN

    // ---- weights + fused dot ----
    float num = 0.f, den = 0.f;
    #pragma unroll
    for (int k = 0; k < 4; ++k) {
        float4 l = lv[k];
        float4 v = iv[k];
        float d0 = v.x - mean, d1 = v.y - mean, d2 = v.z - mean, d3 = v.w - mean;
        float q0 = d0 * d0, q1 = d1 * d1, q2 = d2 * d2, q3 = d3 * d3;
        float e0 = __expf(-q0 * q0), e1 = __expf(-q1 * q1);
        float e2 = __expf(-q2 * q2), e3 = __expf(-q3 * q3);
        num += csx[k] * l.x * e0 + csy[k] * l.y * e1 + csz[k] * l.z * e2 + csw[k] * l.w * e3;
        den += csx[k] * e0 + csy[k] * e1 + csz[k] * e2 + csw[k] * e3;
    }
    #pragma unroll
    for (int off = 32; off > 0; off >>= 1) {
        num += __shfl_down(num, off);
        den += __shfl_down(den, off);
    }
    __syncthreads();   // sm reuse: all threads done reading mean partials
    if (lane == 0) { sm[wid * 2] = num; sm[wid * 2 + 1] = den; }
    __syncthreads();
    if (threadIdx.x == 0)
        g_part2[blockIdx.x] = make_float2(sm[0] + sm[2] + sm[4] + sm[6],
                                          sm[1] + sm[3] + sm[5] + sm[7]);
}

// K3: reduce K2's per-block partials -> per-channel ratio -> loss scalar.
// Wave-parallel over channels (4 waves x 2 ch, 1 barrier).
__global__ void __launch_bounds__(256) final_kernel(float* __restrict__ out) {
    __shared__ float cn[NCH], cd[NCH];
    const int lane = threadIdx.x & 63;
    const int wid  = threadIdx.x >> 6;
    #pragma unroll
    for (int cc = 0; cc < 2; ++cc) {
        const int c = wid * 2 + cc;
        float a = 0.f, b = 0.f;
        for (int t = lane; t < CPB; t += 64) {
            float2 p = g_part2[c * CPB + t];
            a += p.x; b += p.y;
        }
        #pragma unroll
        for (int off = 32; off > 0; off >>= 1) {
            a += __shfl_down(a, off);
            b += __shfl_down(b, off);
        }
        if (lane == 0) { cn[c] = a; cd[c] = b; }
    }
    __syncthreads();
    if (threadIdx.x == 0) {
        float loss = 0.f;
        for (int k = 0; k < NCLS; ++k) {
            float r0 = cn[k]        / (cd[k]        + 1e-6f);
            float r1 = cn[NCLS + k] / (cd[NCLS + k] + 1e-6f);
            loss += 0.5f * (fabsf(r0) + fabsf(r1));   // mean over N=2, sum over K
        }
        out[0] = (float)NCLS - loss;
    }
}

extern "C" void kernel_launch(void* const* d_in, const int* in_sizes, int n_in,
                              void* d_out, int out_size, void* d_ws, size_t ws_size,
                              hipStream_t stream) {
    const float* labels = (const float*)d_in[0];   // (2,4,80,80,80) f32
    const float* img    = (const float*)d_in[1];   // (2,1,80,80,80) f32
    float* out = (float*)d_out;                    // 1 float
    (void)d_ws; (void)ws_size;                     // module-scope scratch

    hipLaunchKernelGGL(convdw_sums_kernel, dim3(NBLK1), dim3(256), 0, stream, labels, img);
    hipLaunchKernelGGL(convh_dot_kernel,   dim3(NBLK2), dim3(256), 0, stream, labels, img);
    hipLaunchKernelGGL(final_kernel,       dim3(1),     dim3(256), 0, stream, out);
}

// Round 3
// 92.278 us; speedup vs baseline: 1.0545x; 1.0545x over previous
//
#include <hip/hip_runtime.h>
#include <math.h>

#define RAD 5
#define SIDE 80
#define SLAB 6400      // 80*80
#define VOL 512000     // 80^3
#define NCH 8          // N*K
#define NCLS 4
#define Q 20           // float4/ushort4 columns per 80-elem row
#define TW 40          // K1 tile extent along w (halo 1.25x)
#define NT 2           // w-tiles per axis (80/40)
#define C1 (SIDE*NT)           // 160 K1 slots per channel
#define NBLK1 (NCH*C1)         // 1280 K1 blocks
#define TBS 22                 // tB row stride in float4
#define NROW (TW+10)           // 50 staged rows per K1 block
#define LROW 100               // padded LDS row stride in floats (400B, 16B-aligned, 100%32=4)
#define NSLOT (LROW/4)         // 25 float4 slots per staged row
#define NBLK2 1000             // K2 blocks (4 h-outputs/thread, 125 per channel)
#define CPB 125                // K2 blocks per channel

// exp(-t^2/32) for t=-5..5 (unnormalized Gaussian, symmetric)
__constant__ float GW[11] = {
    0.45783336177161427f, 0.6065306597126334f, 0.7548396019890073f,
    0.8824969025845955f,  0.969233234476344f,  1.0f,
    0.969233234476344f,   0.8824969025845955f, 0.7548396019890073f,
    0.6065306597126334f,  0.45783336177161427f};

// Module-scope scratch. Slot-based cross-kernel dataflow ONLY:
// R8: device atomics+fences = +100 µs/kernel; R7: grid.sync = +550 µs.
// Kernel boundaries are the only sync primitive used.
__device__ unsigned short g_bufT[(size_t)NCH * VOL];  // bf16 conv'd labels, [c][w][h][d]
__device__ float2 g_part1[NBLK1];             // {S_ip, S_p} per K1 block
__device__ float2 g_part2[NBLK2];             // {num, den} per K2 block

__device__ __forceinline__ unsigned short f2bf(float f) {
    unsigned u = __float_as_uint(f);
    u += 0x7FFFu + ((u >> 16) & 1u);          // round-to-nearest-even
    return (unsigned short)(u >> 16);
}
__device__ __forceinline__ float bf2f(unsigned short h) {
    return __uint_as_float((unsigned)h << 16);
}

// K1: per (c, h, w-tile40).
// R12: stage raw label rows in LDS once (coalesced, 1 read/element) and run the
// d-conv from LDS via 5 aligned b128 reads — the R9/R10 shape re-fetched each
// label element ~5x from global (d-window overlap), ~100 MB of L2/LLC traffic.
// R11 lesson: no big unrolls; loops stay rolled, per-thread live state small.
__global__ void __launch_bounds__(256) convdw_sums_kernel(
        const float* __restrict__ labels, const float* __restrict__ img) {
    const int tile = blockIdx.x;
    const int c   = tile / C1;
    const int rem = tile % C1;
    const int h   = rem / NT;
    const int w0  = (rem % NT) * TW;
    const int n   = c >> 2;

    __shared__ float  lraw[NROW * LROW];     // 20 KB raw rows, zero-padded halo
    __shared__ float4 tB[NROW * TBS];        // 17.6 KB d-conv result rows
    __shared__ float sm[8];

    const float4* labc4 = (const float4*)(labels + ((size_t)c * SIDE + h) * SLAB);
    const float4* imgc4 = (const float4*)(img + ((size_t)n * SIDE + h) * SLAB);

    // ---- stage: lraw[row][8 + d] = labels[c][h][w0-5+row][d], pads zero ----
    for (int i = threadIdx.x; i < NROW * NSLOT; i += 256) {
        const int row = i / NSLOT, slot = i - (i / NSLOT) * NSLOT;
        const int w = w0 - RAD + row;
        float4 v = make_float4(0.f, 0.f, 0.f, 0.f);
        if (slot >= 2 && slot < 22 && (unsigned)w < SIDE)
            v = labc4[(size_t)w * Q + (slot - 2)];
        *(float4*)&lraw[row * LROW + slot * 4] = v;
    }
    __syncthreads();

    // ---- d-conv from LDS + fused channel sums ----
    float sip = 0.f, sp = 0.f;
    for (int i = threadIdx.x; i < NROW * Q; i += 256) {
        const int r = i / Q, q = i - (i / Q) * Q;
        const float* L = &lraw[r * LROW + 4 * q];   // a[k] = label at d = 4q-8+k
        float a[20];
        #pragma unroll
        for (int j = 0; j < 5; ++j) {
            float4 v = *(const float4*)&L[4 * j];
            a[4 * j] = v.x; a[4 * j + 1] = v.y;
            a[4 * j + 2] = v.z; a[4 * j + 3] = v.w;
        }
        if (r >= RAD && r < RAD + TW) {   // central rows: fused channel sums
            const int w = w0 - RAD + r;
            float4 v = imgc4[(size_t)w * Q + q];
            sip += a[8] * v.x + a[9] * v.y + a[10] * v.z + a[11] * v.w;
            sp  += a[8] + a[9] + a[10] + a[11];
        }
        float s0 = 0.f, s1 = 0.f, s2 = 0.f, s3 = 0.f;
        #pragma unroll
        for (int t = 0; t < 11; ++t) {
            float g = GW[t];
            s0 += g * a[t + 3]; s1 += g * a[t + 4];
            s2 += g * a[t + 5]; s3 += g * a[t + 6];
        }
        tB[r * TBS + q] = make_float4(s0, s1, s2, s3);
    }
    // block-reduce sums (same barrier covers tB completion + sm visibility)
    #pragma unroll
    for (int off = 32; off > 0; off >>= 1) {
        sip += __shfl_down(sip, off);
        sp  += __shfl_down(sp, off);
    }
    const int lane = threadIdx.x & 63;
    const int wid  = threadIdx.x >> 6;
    if (lane == 0) { sm[wid * 2] = sip; sm[wid * 2 + 1] = sp; }
    __syncthreads();
    if (threadIdx.x == 0)
        g_part1[tile] = make_float2(sm[0] + sm[2] + sm[4] + sm[6],
                                    sm[1] + sm[3] + sm[5] + sm[7]);
    // w-conv (11-tap LDS gather) + transposed bf16 ushort4 store
    ushort4* out4 = (ushort4*)g_bufT + ((size_t)c * VOL + (size_t)h * SIDE) / 4;
    for (int i = threadIdx.x; i < TW * Q; i += 256) {
        const int rl = i / Q, q = i - (i / Q) * Q;
        float sx = 0.f, sy = 0.f, sz = 0.f, sw = 0.f;
        #pragma unroll
        for (int t = 0; t < 11; ++t) {
            float g = GW[t];
            float4 v = tB[(rl + t) * TBS + q];
            sx += g * v.x; sy += g * v.y; sz += g * v.z; sw += g * v.w;
        }
        ushort4 o;
        o.x = f2bf(sx); o.y = f2bf(sy); o.z = f2bf(sz); o.w = f2bf(sw);
        out4[(size_t)(w0 + rl) * (SLAB / 4) + q] = o;
    }
}

// K2: register sliding-window conv along H from bf16 g_bufT (no LDS conv),
// fused weight + dot. Thread = (c, hq, w, q) producing 4 h-outputs.
// (Reverted verbatim to the 88.4 µs R10 shape — R11's reorder regressed on
// VGPR pressure across the barrier.)
__global__ void __launch_bounds__(256) convh_dot_kernel(
        const float* __restrict__ labels, const float* __restrict__ img) {
    const int c   = blockIdx.x / CPB;
    const int rem = (blockIdx.x % CPB) * 256 + threadIdx.x;   // 0..31999
    const int hq  = rem / 1600;          // 20 h-quads
    const int r2  = rem % 1600;
    const int w   = r2 / Q;
    const int q   = r2 % Q;
    const int h0  = hq * 4;
    const int n   = c >> 2;

    __shared__ float sm[8];
    __shared__ float s_mean;

    // per-channel mean from K1 partials (block-redundant; L2-resident, 1.3 KB)
    float a = 0.f, b = 0.f;
    for (int t = threadIdx.x; t < C1; t += 256) {
        float2 p = g_part1[c * C1 + t];
        a += p.x; b += p.y;
    }
    #pragma unroll
    for (int off = 32; off > 0; off >>= 1) {
        a += __shfl_down(a, off);
        b += __shfl_down(b, off);
    }
    const int lane = threadIdx.x & 63;
    const int wid  = threadIdx.x >> 6;
    if (lane == 0) { sm[wid * 2] = a; sm[wid * 2 + 1] = b; }
    __syncthreads();
    if (threadIdx.x == 0)
        s_mean = (sm[0] + sm[2] + sm[4] + sm[6]) /
                 (sm[1] + sm[3] + sm[5] + sm[7] + 5.12f);   // VOL*EPS_MEAN
    __syncthreads();
    const float mean = s_mean;

    // sliding window: g_bufT[c][w][h0-5 .. h0+8][q]  (14 ushort4, OOB -> 0)
    const ushort4* bc4 = (const ushort4*)g_bufT + ((size_t)c * VOL + (size_t)w * SLAB) / 4;
    float4 win[14];
    #pragma unroll
    for (int m = 0; m < 14; ++m) {
        int hh = h0 - RAD + m;
        if ((unsigned)hh < SIDE) {
            ushort4 u = bc4[hh * Q + q];
            win[m] = make_float4(bf2f(u.x), bf2f(u.y), bf2f(u.z), bf2f(u.w));
        } else {
            win[m] = make_float4(0.f, 0.f, 0.f, 0.f);
        }
    }
    const float4* labp4 = (const float4*)labels + (size_t)c * (VOL / 4);
    const float4* imgp4 = (const float4*)img + (size_t)n * (VOL / 4);
    float num = 0.f, den = 0.f;
    #pragma unroll
    for (int k = 0; k < 4; ++k) {
        float sx = 0.f, sy = 0.f, sz = 0.f, sw = 0.f;
        #pragma unroll
        for (int t = 0; t < 11; ++t) {
            float g = GW[t];
            float4 v = win[k + t];
            sx += g * v.x; sy += g * v.y; sz += g * v.z; sw += g * v.w;
        }
        size_t gi = (size_t)(h0 + k) * (SLAB / 4) + (size_t)w * Q + q;
        float4 l = labp4[gi];
        float4 v = imgp4[gi];
        float d0 = v.x - mean, d1 = v.y - mean, d2 = v.z - mean, d3 = v.w - mean;
        float q0 = d0 * d0, q1 = d1 * d1, q2 = d2 * d2, q3 = d3 * d3;
        float e0 = __expf(-q0 * q0), e1 = __expf(-q1 * q1);
        float e2 = __expf(-q2 * q2), e3 = __expf(-q3 * q3);
        num += sx * l.x * e0 + sy * l.y * e1 + sz * l.z * e2 + sw * l.w * e3;
        den += sx * e0 + sy * e1 + sz * e2 + sw * e3;
    }
    #pragma unroll
    for (int off = 32; off > 0; off >>= 1) {
        num += __shfl_down(num, off);
        den += __shfl_down(den, off);
    }
    if (lane == 0) { sm[wid * 2] = num; sm[wid * 2 + 1] = den; }
    __syncthreads();
    if (threadIdx.x == 0)
        g_part2[blockIdx.x] = make_float2(sm[0] + sm[2] + sm[4] + sm[6],
                                          sm[1] + sm[3] + sm[5] + sm[7]);
}

// K3: reduce K2's per-block partials -> per-channel ratio -> loss scalar.
// Wave-parallel over channels (4 waves x 2 ch, 1 barrier).
__global__ void __launch_bounds__(256) final_kernel(float* __restrict__ out) {
    __shared__ float cn[NCH], cd[NCH];
    const int lane = threadIdx.x & 63;
    const int wid  = threadIdx.x >> 6;
    #pragma unroll
    for (int cc = 0; cc < 2; ++cc) {
        const int c = wid * 2 + cc;
        float a = 0.f, b = 0.f;
        for (int t = lane; t < CPB; t += 64) {
            float2 p = g_part2[c * CPB + t];
            a += p.x; b += p.y;
        }
        #pragma unroll
        for (int off = 32; off > 0; off >>= 1) {
            a += __shfl_down(a, off);
            b += __shfl_down(b, off);
        }
        if (lane == 0) { cn[c] = a; cd[c] = b; }
    }
    __syncthreads();
    if (threadIdx.x == 0) {
        float loss = 0.f;
        for (int k = 0; k < NCLS; ++k) {
            float r0 = cn[k]        / (cd[k]        + 1e-6f);
            float r1 = cn[NCLS + k] / (cd[NCLS + k] + 1e-6f);
            loss += 0.5f * (fabsf(r0) + fabsf(r1));   // mean over N=2, sum over K
        }
        out[0] = (float)NCLS - loss;
    }
}

extern "C" void kernel_launch(void* const* d_in, const int* in_sizes, int n_in,
                              void* d_out, int out_size, void* d_ws, size_t ws_size,
                              hipStream_t stream) {
    const float* labels = (const float*)d_in[0];   // (2,4,80,80,80) f32
    const float* img    = (const float*)d_in[1];   // (2,1,80,80,80) f32
    float* out = (float*)d_out;                    // 1 float
    (void)d_ws; (void)ws_size;                     // module-scope scratch

    hipLaunchKernelGGL(convdw_sums_kernel, dim3(NBLK1), dim3(256), 0, stream, labels, img);
    hipLaunchKernelGGL(convh_dot_kernel,   dim3(NBLK2), dim3(256), 0, stream, labels, img);
    hipLaunchKernelGGL(final_kernel,       dim3(1),     dim3(256), 0, stream, out);
}

// Round 4
// 89.148 us; speedup vs baseline: 1.0915x; 1.0351x over previous
//
#include <hip/hip_runtime.h>
#include <math.h>

#define RAD 5
#define SIDE 80
#define SLAB 6400      // 80*80
#define VOL 512000     // 80^3
#define NCH 8          // N*K
#define NCLS 4
#define Q 20           // float4/ushort4 columns per 80-elem row
#define TW 40          // K1 tile extent along w (halo 1.25x; 1280 blocks = 5/CU resident)
#define NT 2           // w-tiles per axis (80/40)
#define C1 (SIDE*NT)           // 160 K1 slots per channel
#define NBLK1 (NCH*C1)         // 1280 K1 blocks
#define TBS 22                 // tB row stride in float4
#define NBLK2 1000             // K2 blocks (4 h-outputs/thread, 125 per channel)
#define CPB 125                // K2 blocks per channel

// exp(-t^2/32) for t=-5..5 (unnormalized Gaussian, symmetric)
__constant__ float GW[11] = {
    0.45783336177161427f, 0.6065306597126334f, 0.7548396019890073f,
    0.8824969025845955f,  0.969233234476344f,  1.0f,
    0.969233234476344f,   0.8824969025845955f, 0.7548396019890073f,
    0.6065306597126334f,  0.45783336177161427f};

// Module-scope scratch. Slot-based cross-kernel dataflow ONLY:
// R8: device atomics+fences = +100 µs/kernel; R7: grid.sync = +550 µs.
// Kernel boundaries are the only sync primitive used.
// R12 lesson: K1 is residency-critical (needs 5 blocks/CU, LDS <= 32 KB).
__device__ unsigned short g_bufT[(size_t)NCH * VOL];  // bf16 conv'd labels, [c][w][h][d]
__device__ float2 g_part1[NBLK1];             // {S_ip, S_p} per K1 block
__device__ float2 g_part2[NBLK2];             // {num, den} per K2 block

__device__ __forceinline__ unsigned short f2bf(float f) {
    unsigned u = __float_as_uint(f);
    u += 0x7FFFu + ((u >> 16) & 1u);          // round-to-nearest-even
    return (unsigned short)(u >> 16);
}
__device__ __forceinline__ float bf2f(unsigned short h) {
    return __uint_as_float((unsigned)h << 16);
}

// K1: per (c, h, w-tile40): d-conv via register window from global,
// fused channel sums, w-conv via LDS gather, transposed bf16 store to g_bufT.
// (Verbatim the 88.4 µs R10 shape — R11 unroll and R12 LDS-staging both regressed.)
__global__ void __launch_bounds__(256) convdw_sums_kernel(
        const float* __restrict__ labels, const float* __restrict__ img) {
    const int tile = blockIdx.x;
    const int c   = tile / C1;
    const int rem = tile % C1;
    const int h   = rem / NT;
    const int w0  = (rem % NT) * TW;
    const int n   = c >> 2;

    __shared__ float4 tB[(TW + 10) * TBS];   // d-conv result rows w0-5..w0+TW+4
    __shared__ float sm[8];

    const float4* labc4 = (const float4*)(labels + ((size_t)c * SIDE + h) * SLAB);
    const float4* imgc4 = (const float4*)(img + ((size_t)n * SIDE + h) * SLAB);

    float sip = 0.f, sp = 0.f;
    for (int i = threadIdx.x; i < (TW + 10) * Q; i += 256) {
        const int r = i / Q, q = i - (i / Q) * Q;
        const int w = w0 - RAD + r;
        float a[20];
        #pragma unroll
        for (int j = 0; j < 20; ++j) a[j] = 0.f;
        if ((unsigned)w < SIDE) {
            const float4* row = labc4 + (size_t)w * Q;
            #pragma unroll
            for (int j = 0; j < 5; ++j) {
                int qq = q - 2 + j;
                if (qq >= 0 && qq < Q) {
                    float4 v = row[qq];
                    a[4 * j] = v.x; a[4 * j + 1] = v.y;
                    a[4 * j + 2] = v.z; a[4 * j + 3] = v.w;
                }
            }
            if (r >= RAD && r < RAD + TW) {   // central rows: fused channel sums
                float4 v = imgc4[(size_t)w * Q + q];
                sip += a[8] * v.x + a[9] * v.y + a[10] * v.z + a[11] * v.w;
                sp  += a[8] + a[9] + a[10] + a[11];
            }
        }
        float s0 = 0.f, s1 = 0.f, s2 = 0.f, s3 = 0.f;
        #pragma unroll
        for (int t = 0; t < 11; ++t) {
            float g = GW[t];
            s0 += g * a[t + 3]; s1 += g * a[t + 4];
            s2 += g * a[t + 5]; s3 += g * a[t + 6];
        }
        tB[r * TBS + q] = make_float4(s0, s1, s2, s3);
    }
    // block-reduce sums (same barrier covers tB completion + sm visibility)
    #pragma unroll
    for (int off = 32; off > 0; off >>= 1) {
        sip += __shfl_down(sip, off);
        sp  += __shfl_down(sp, off);
    }
    const int lane = threadIdx.x & 63;
    const int wid  = threadIdx.x >> 6;
    if (lane == 0) { sm[wid * 2] = sip; sm[wid * 2 + 1] = sp; }
    __syncthreads();
    if (threadIdx.x == 0)
        g_part1[tile] = make_float2(sm[0] + sm[2] + sm[4] + sm[6],
                                    sm[1] + sm[3] + sm[5] + sm[7]);
    // w-conv (11-tap LDS gather) + transposed bf16 ushort4 store
    ushort4* out4 = (ushort4*)g_bufT + ((size_t)c * VOL + (size_t)h * SIDE) / 4;
    for (int i = threadIdx.x; i < TW * Q; i += 256) {
        const int rl = i / Q, q = i - (i / Q) * Q;
        float sx = 0.f, sy = 0.f, sz = 0.f, sw = 0.f;
        #pragma unroll
        for (int t = 0; t < 11; ++t) {
            float g = GW[t];
            float4 v = tB[(rl + t) * TBS + q];
            sx += g * v.x; sy += g * v.y; sz += g * v.z; sw += g * v.w;
        }
        ushort4 o;
        o.x = f2bf(sx); o.y = f2bf(sy); o.z = f2bf(sz); o.w = f2bf(sw);
        out4[(size_t)(w0 + rl) * (SLAB / 4) + q] = o;
    }
}

// K2: register sliding-window conv along H from bf16 g_bufT, fused weight+dot.
// R13 (gentle version of R11's failed reorder, VGPR-light):
//  - g_part1 loads issued FIRST so the mean reduce needs only a counted
//    vmcnt (not a full drain of the 22 later loads);
//  - win issued as raw ushort4 (28 VGPR) + lv/iv (32) before the prologue
//    => prologue latency overlaps load latency instead of adding;
//  - one barrier, per-thread mean divide; convert + all compute after.
__global__ void __launch_bounds__(256) convh_dot_kernel(
        const float* __restrict__ labels, const float* __restrict__ img) {
    const int c   = blockIdx.x / CPB;
    const int rem = (blockIdx.x % CPB) * 256 + threadIdx.x;   // 0..31999
    const int hq  = rem / 1600;          // 20 h-quads
    const int r2  = rem % 1600;
    const int w   = r2 / Q;
    const int q   = r2 % Q;
    const int h0  = hq * 4;
    const int n   = c >> 2;

    __shared__ float sm[8];
    const int lane = threadIdx.x & 63;
    const int wid  = threadIdx.x >> 6;

    // ---- oldest loads first: mean partials (2 per thread) ----
    float a = 0.f, b = 0.f;
    {
        float2 p0 = make_float2(0.f, 0.f);
        if (threadIdx.x < C1) p0 = g_part1[c * C1 + threadIdx.x];   // C1=160
        a = p0.x; b = p0.y;
    }

    // ---- issue mean-independent loads (stay in flight through the reduce) ----
    const ushort4* bc4 = (const ushort4*)g_bufT + ((size_t)c * VOL + (size_t)w * SLAB) / 4;
    ushort4 wraw[14];
    #pragma unroll
    for (int m = 0; m < 14; ++m) {
        int hh = h0 - RAD + m;
        if ((unsigned)hh < SIDE) wraw[m] = bc4[hh * Q + q];
        else { wraw[m].x = 0; wraw[m].y = 0; wraw[m].z = 0; wraw[m].w = 0; }
    }
    const float4* labp4 = (const float4*)labels + (size_t)c * (VOL / 4);
    const float4* imgp4 = (const float4*)img + (size_t)n * (VOL / 4);
    float4 lv[4], iv[4];
    #pragma unroll
    for (int k = 0; k < 4; ++k) {
        size_t gi = (size_t)(h0 + k) * (SLAB / 4) + (size_t)w * Q + q;
        lv[k] = labp4[gi];
        iv[k] = imgp4[gi];
    }

    // ---- mean reduce (needs only the 2 oldest loads) ----
    #pragma unroll
    for (int off = 32; off > 0; off >>= 1) {
        a += __shfl_down(a, off);
        b += __shfl_down(b, off);
    }
    if (lane == 0) { sm[wid * 2] = a; sm[wid * 2 + 1] = b; }
    __syncthreads();
    const float mean = (sm[0] + sm[2] + sm[4] + sm[6]) /
                       (sm[1] + sm[3] + sm[5] + sm[7] + 5.12f);   // VOL*EPS_MEAN

    // ---- convert window, conv + weights + fused dot (as 88.4 baseline) ----
    float4 win[14];
    #pragma unroll
    for (int m = 0; m < 14; ++m)
        win[m] = make_float4(bf2f(wraw[m].x), bf2f(wraw[m].y),
                             bf2f(wraw[m].z), bf2f(wraw[m].w));
    float num = 0.f, den = 0.f;
    #pragma unroll
    for (int k = 0; k < 4; ++k) {
        float sx = 0.f, sy = 0.f, sz = 0.f, sw = 0.f;
        #pragma unroll
        for (int t = 0; t < 11; ++t) {
            float g = GW[t];
            float4 v = win[k + t];
            sx += g * v.x; sy += g * v.y; sz += g * v.z; sw += g * v.w;
        }
        float4 l = lv[k];
        float4 v = iv[k];
        float d0 = v.x - mean, d1 = v.y - mean, d2 = v.z - mean, d3 = v.w - mean;
        float q0 = d0 * d0, q1 = d1 * d1, q2 = d2 * d2, q3 = d3 * d3;
        float e0 = __expf(-q0 * q0), e1 = __expf(-q1 * q1);
        float e2 = __expf(-q2 * q2), e3 = __expf(-q3 * q3);
        num += sx * l.x * e0 + sy * l.y * e1 + sz * l.z * e2 + sw * l.w * e3;
        den += sx * e0 + sy * e1 + sz * e2 + sw * e3;
    }
    #pragma unroll
    for (int off = 32; off > 0; off >>= 1) {
        num += __shfl_down(num, off);
        den += __shfl_down(den, off);
    }
    __syncthreads();   // all threads done reading sm (mean) before reuse
    if (lane == 0) { sm[wid * 2] = num; sm[wid * 2 + 1] = den; }
    __syncthreads();
    if (threadIdx.x == 0)
        g_part2[blockIdx.x] = make_float2(sm[0] + sm[2] + sm[4] + sm[6],
                                          sm[1] + sm[3] + sm[5] + sm[7]);
}

// K3: reduce K2's per-block partials -> per-channel ratio -> loss scalar.
// Wave-parallel over channels (4 waves x 2 ch, 1 barrier).
__global__ void __launch_bounds__(256) final_kernel(float* __restrict__ out) {
    __shared__ float cn[NCH], cd[NCH];
    const int lane = threadIdx.x & 63;
    const int wid  = threadIdx.x >> 6;
    #pragma unroll
    for (int cc = 0; cc < 2; ++cc) {
        const int c = wid * 2 + cc;
        float a = 0.f, b = 0.f;
        for (int t = lane; t < CPB; t += 64) {
            float2 p = g_part2[c * CPB + t];
            a += p.x; b += p.y;
        }
        #pragma unroll
        for (int off = 32; off > 0; off >>= 1) {
            a += __shfl_down(a, off);
            b += __shfl_down(b, off);
        }
        if (lane == 0) { cn[c] = a; cd[c] = b; }
    }
    __syncthreads();
    if (threadIdx.x == 0) {
        float loss = 0.f;
        for (int k = 0; k < NCLS; ++k) {
            float r0 = cn[k]        / (cd[k]        + 1e-6f);
            float r1 = cn[NCLS + k] / (cd[NCLS + k] + 1e-6f);
            loss += 0.5f * (fabsf(r0) + fabsf(r1));   // mean over N=2, sum over K
        }
        out[0] = (float)NCLS - loss;
    }
}

extern "C" void kernel_launch(void* const* d_in, const int* in_sizes, int n_in,
                              void* d_out, int out_size, void* d_ws, size_t ws_size,
                              hipStream_t stream) {
    const float* labels = (const float*)d_in[0];   // (2,4,80,80,80) f32
    const float* img    = (const float*)d_in[1];   // (2,1,80,80,80) f32
    float* out = (float*)d_out;                    // 1 float
    (void)d_ws; (void)ws_size;                     // module-scope scratch

    hipLaunchKernelGGL(convdw_sums_kernel, dim3(NBLK1), dim3(256), 0, stream, labels, img);
    hipLaunchKernelGGL(convh_dot_kernel,   dim3(NBLK2), dim3(256), 0, stream, labels, img);
    hipLaunchKernelGGL(final_kernel,       dim3(1),     dim3(256), 0, stream, out);
}

// Round 5
// 85.847 us; speedup vs baseline: 1.1335x; 1.0384x over previous
//
#include <hip/hip_runtime.h>
#include <math.h>

#define RAD 5
#define SIDE 80
#define SLAB 6400      // 80*80
#define VOL 512000     // 80^3
#define NCH 8          // N*K
#define NCLS 4
#define Q 20           // float4/ushort4 columns per 80-elem row
#define TW 40          // K1 tile extent along w (halo 1.25x; 1280 blocks = 5/CU resident)
#define NT 2           // w-tiles per axis (80/40)
#define C1 (SIDE*NT)           // 160 K1 slots per channel
#define NBLK1 (NCH*C1)         // 1280 K1 blocks
#define TBS 22                 // tB row stride in float4
#define NBLK2 1280             // K2 blocks: (c, w, h-half) = 8*80*2, 5/CU exact
#define CPB 160                // K2 blocks per channel
#define SBS 84                 // K2 LDS row stride in floats (21 float4, 336 B)

// exp(-t^2/32) for t=-5..5 (unnormalized Gaussian, symmetric)
__constant__ float GW[11] = {
    0.45783336177161427f, 0.6065306597126334f, 0.7548396019890073f,
    0.8824969025845955f,  0.969233234476344f,  1.0f,
    0.969233234476344f,   0.8824969025845955f, 0.7548396019890073f,
    0.6065306597126334f,  0.45783336177161427f};

// Module-scope scratch. Slot-based cross-kernel dataflow ONLY:
// R8: device atomics+fences = +100 µs/kernel; R7: grid.sync = +550 µs.
// Kernel boundaries are the only sync primitive used.
// R12 lesson: residency-critical kernels need LDS small enough for 5 blocks/CU.
__device__ unsigned short g_bufT[(size_t)NCH * VOL];  // bf16 conv'd labels, [c][w][h][d]
__device__ float2 g_part1[NBLK1];             // {S_ip, S_p} per K1 block
__device__ float2 g_part2[NBLK2];             // {num, den} per K2 block

__device__ __forceinline__ unsigned short f2bf(float f) {
    unsigned u = __float_as_uint(f);
    u += 0x7FFFu + ((u >> 16) & 1u);          // round-to-nearest-even
    return (unsigned short)(u >> 16);
}
__device__ __forceinline__ float bf2f(unsigned short h) {
    return __uint_as_float((unsigned)h << 16);
}

// K1: per (c, h, w-tile40): d-conv via register window from global,
// fused channel sums, w-conv via LDS gather, transposed bf16 store to g_bufT.
// (Verbatim the 88.4 µs R10 shape — R11 unroll and R12 LDS-staging both regressed.)
__global__ void __launch_bounds__(256) convdw_sums_kernel(
        const float* __restrict__ labels, const float* __restrict__ img) {
    const int tile = blockIdx.x;
    const int c   = tile / C1;
    const int rem = tile % C1;
    const int h   = rem / NT;
    const int w0  = (rem % NT) * TW;
    const int n   = c >> 2;

    __shared__ float4 tB[(TW + 10) * TBS];   // d-conv result rows w0-5..w0+TW+4
    __shared__ float sm[8];

    const float4* labc4 = (const float4*)(labels + ((size_t)c * SIDE + h) * SLAB);
    const float4* imgc4 = (const float4*)(img + ((size_t)n * SIDE + h) * SLAB);

    float sip = 0.f, sp = 0.f;
    for (int i = threadIdx.x; i < (TW + 10) * Q; i += 256) {
        const int r = i / Q, q = i - (i / Q) * Q;
        const int w = w0 - RAD + r;
        float a[20];
        #pragma unroll
        for (int j = 0; j < 20; ++j) a[j] = 0.f;
        if ((unsigned)w < SIDE) {
            const float4* row = labc4 + (size_t)w * Q;
            #pragma unroll
            for (int j = 0; j < 5; ++j) {
                int qq = q - 2 + j;
                if (qq >= 0 && qq < Q) {
                    float4 v = row[qq];
                    a[4 * j] = v.x; a[4 * j + 1] = v.y;
                    a[4 * j + 2] = v.z; a[4 * j + 3] = v.w;
                }
            }
            if (r >= RAD && r < RAD + TW) {   // central rows: fused channel sums
                float4 v = imgc4[(size_t)w * Q + q];
                sip += a[8] * v.x + a[9] * v.y + a[10] * v.z + a[11] * v.w;
                sp  += a[8] + a[9] + a[10] + a[11];
            }
        }
        float s0 = 0.f, s1 = 0.f, s2 = 0.f, s3 = 0.f;
        #pragma unroll
        for (int t = 0; t < 11; ++t) {
            float g = GW[t];
            s0 += g * a[t + 3]; s1 += g * a[t + 4];
            s2 += g * a[t + 5]; s3 += g * a[t + 6];
        }
        tB[r * TBS + q] = make_float4(s0, s1, s2, s3);
    }
    // block-reduce sums (same barrier covers tB completion + sm visibility)
    #pragma unroll
    for (int off = 32; off > 0; off >>= 1) {
        sip += __shfl_down(sip, off);
        sp  += __shfl_down(sp, off);
    }
    const int lane = threadIdx.x & 63;
    const int wid  = threadIdx.x >> 6;
    if (lane == 0) { sm[wid * 2] = sip; sm[wid * 2 + 1] = sp; }
    __syncthreads();
    if (threadIdx.x == 0)
        g_part1[tile] = make_float2(sm[0] + sm[2] + sm[4] + sm[6],
                                    sm[1] + sm[3] + sm[5] + sm[7]);
    // w-conv (11-tap LDS gather) + transposed bf16 ushort4 store
    ushort4* out4 = (ushort4*)g_bufT + ((size_t)c * VOL + (size_t)h * SIDE) / 4;
    for (int i = threadIdx.x; i < TW * Q; i += 256) {
        const int rl = i / Q, q = i - (i / Q) * Q;
        float sx = 0.f, sy = 0.f, sz = 0.f, sw = 0.f;
        #pragma unroll
        for (int t = 0; t < 11; ++t) {
            float g = GW[t];
            float4 v = tB[(rl + t) * TBS + q];
            sx += g * v.x; sy += g * v.y; sz += g * v.z; sw += g * v.w;
        }
        ushort4 o;
        o.x = f2bf(sx); o.y = f2bf(sy); o.z = f2bf(sz); o.w = f2bf(sw);
        out4[(size_t)(w0 + rl) * (SLAB / 4) + q] = o;
    }
}

// K2 (R14 restructure): block = (c, w, h-half). Stage the contiguous
// g_bufT[c][w][hh0-5..hh0+44][:] chunk (8 KB) into LDS as f32 ONCE
// (coalesced, 1.25x halo vs the old per-thread 3.5x window redundancy;
// bf16 cvt amortized to staging), h-conv from LDS, fused weights + dot.
// 1280 blocks = 5/CU exact; LDS 16.8 KB -> residency not limiting (R12 lesson).
__global__ void __launch_bounds__(256) convh_dot_kernel(
        const float* __restrict__ labels, const float* __restrict__ img) {
    const int c   = blockIdx.x / CPB;
    const int rw  = blockIdx.x % CPB;
    const int w   = rw >> 1;
    const int hh0 = (rw & 1) * 40;
    const int n   = c >> 2;

    __shared__ float sB[50 * SBS];   // f32 window rows hh0-5..hh0+44
    __shared__ float sm[8];
    const int lane = threadIdx.x & 63;
    const int wid  = threadIdx.x >> 6;

    // oldest loads: mean partials (1 per thread, C1=160)
    float a = 0.f, b = 0.f;
    if (threadIdx.x < C1) {
        float2 p = g_part1[c * C1 + threadIdx.x];
        a = p.x; b = p.y;
    }

    // stage: contiguous bf16 chunk -> f32 LDS rows (zero-pad OOB halo)
    const ushort4* src = (const ushort4*)g_bufT + ((size_t)c * VOL + (size_t)w * SLAB) / 4;
    for (int i = threadIdx.x; i < 50 * Q; i += 256) {
        const int row = i / Q, s = i - (i / Q) * Q;
        const int hh = hh0 - RAD + row;
        float4 v = make_float4(0.f, 0.f, 0.f, 0.f);
        if ((unsigned)hh < SIDE) {
            ushort4 u = src[hh * Q + s];
            v = make_float4(bf2f(u.x), bf2f(u.y), bf2f(u.z), bf2f(u.w));
        }
        *(float4*)&sB[row * SBS + s * 4] = v;
    }

    // mean reduce (only needs the g_part1 loads)
    #pragma unroll
    for (int off = 32; off > 0; off >>= 1) {
        a += __shfl_down(a, off);
        b += __shfl_down(b, off);
    }
    if (lane == 0) { sm[wid * 2] = a; sm[wid * 2 + 1] = b; }
    __syncthreads();   // covers sB staging + sm visibility
    const float mean = (sm[0] + sm[2] + sm[4] + sm[6]) /
                       (sm[1] + sm[3] + sm[5] + sm[7] + 5.12f);   // VOL*EPS_MEAN

    // h-conv from LDS + fused weights + dot.  800 items = (40 h) x (20 q)
    const float4* labp4 = (const float4*)labels + (size_t)c * (VOL / 4);
    const float4* imgp4 = (const float4*)img + (size_t)n * (VOL / 4);
    float num = 0.f, den = 0.f;
    for (int i = threadIdx.x; i < TW * Q; i += 256) {
        const int hl = i / Q, q = i - (i / Q) * Q;
        const int h  = hh0 + hl;
        float sx = 0.f, sy = 0.f, sz = 0.f, sw = 0.f;
        #pragma unroll
        for (int t = 0; t < 11; ++t) {
            float g = GW[t];
            float4 v = *(const float4*)&sB[(hl + t) * SBS + q * 4];
            sx += g * v.x; sy += g * v.y; sz += g * v.z; sw += g * v.w;
        }
        const int li = h * (SLAB / 4) + w * Q + q;
        float4 l = labp4[li];
        float4 v = imgp4[li];
        float d0 = v.x - mean, d1 = v.y - mean, d2 = v.z - mean, d3 = v.w - mean;
        float q0 = d0 * d0, q1 = d1 * d1, q2 = d2 * d2, q3 = d3 * d3;
        float e0 = __expf(-q0 * q0), e1 = __expf(-q1 * q1);
        float e2 = __expf(-q2 * q2), e3 = __expf(-q3 * q3);
        num += sx * l.x * e0 + sy * l.y * e1 + sz * l.z * e2 + sw * l.w * e3;
        den += sx * e0 + sy * e1 + sz * e2 + sw * e3;
    }
    #pragma unroll
    for (int off = 32; off > 0; off >>= 1) {
        num += __shfl_down(num, off);
        den += __shfl_down(den, off);
    }
    __syncthreads();   // all threads done reading sm (mean) before reuse
    if (lane == 0) { sm[wid * 2] = num; sm[wid * 2 + 1] = den; }
    __syncthreads();
    if (threadIdx.x == 0)
        g_part2[blockIdx.x] = make_float2(sm[0] + sm[2] + sm[4] + sm[6],
                                          sm[1] + sm[3] + sm[5] + sm[7]);
}

// K3: reduce K2's per-block partials -> per-channel ratio -> loss scalar.
// Wave-parallel over channels (4 waves x 2 ch, 1 barrier). CPB=160 now.
__global__ void __launch_bounds__(256) final_kernel(float* __restrict__ out) {
    __shared__ float cn[NCH], cd[NCH];
    const int lane = threadIdx.x & 63;
    const int wid  = threadIdx.x >> 6;
    #pragma unroll
    for (int cc = 0; cc < 2; ++cc) {
        const int c = wid * 2 + cc;
        float a = 0.f, b = 0.f;
        for (int t = lane; t < CPB; t += 64) {
            float2 p = g_part2[c * CPB + t];
            a += p.x; b += p.y;
        }
        #pragma unroll
        for (int off = 32; off > 0; off >>= 1) {
            a += __shfl_down(a, off);
            b += __shfl_down(b, off);
        }
        if (lane == 0) { cn[c] = a; cd[c] = b; }
    }
    __syncthreads();
    if (threadIdx.x == 0) {
        float loss = 0.f;
        for (int k = 0; k < NCLS; ++k) {
            float r0 = cn[k]        / (cd[k]        + 1e-6f);
            float r1 = cn[NCLS + k] / (cd[NCLS + k] + 1e-6f);
            loss += 0.5f * (fabsf(r0) + fabsf(r1));   // mean over N=2, sum over K
        }
        out[0] = (float)NCLS - loss;
    }
}

extern "C" void kernel_launch(void* const* d_in, const int* in_sizes, int n_in,
                              void* d_out, int out_size, void* d_ws, size_t ws_size,
                              hipStream_t stream) {
    const float* labels = (const float*)d_in[0];   // (2,4,80,80,80) f32
    const float* img    = (const float*)d_in[1];   // (2,1,80,80,80) f32
    float* out = (float*)d_out;                    // 1 float
    (void)d_ws; (void)ws_size;                     // module-scope scratch

    hipLaunchKernelGGL(convdw_sums_kernel, dim3(NBLK1), dim3(256), 0, stream, labels, img);
    hipLaunchKernelGGL(convh_dot_kernel,   dim3(NBLK2), dim3(256), 0, stream, labels, img);
    hipLaunchKernelGGL(final_kernel,       dim3(1),     dim3(256), 0, stream, out);
}